// Round 1
// baseline (205.244 us; speedup 1.0000x reference)
//
#include <hip/hip_runtime.h>
#include <math.h>

// Problem constants (match reference setup_inputs)
#define Bn 4096
#define Sn 2048
#define BLOCK 256
#define CHUNK (Sn / BLOCK)   // 8 steps per thread

// Stable log-sum-exp of two finite values: max + log(1 + exp(min-max))
__device__ __forceinline__ float lse2(float a, float b) {
    float m = fmaxf(a, b);
    float d = fminf(a, b) - m;           // <= 0, finite
    return m + __logf(1.0f + __expf(d));
}

struct Mat {
    float m00, m01, m10, m11;
};

// Ordered composition in the (+, lse) semiring: result = P then Q in time.
// R[i][j] = lse_k( P[i][k] + Q[k][j] )
__device__ __forceinline__ Mat compose(const Mat& P, const Mat& Q) {
    Mat r;
    r.m00 = lse2(P.m00 + Q.m00, P.m01 + Q.m10);
    r.m01 = lse2(P.m00 + Q.m01, P.m01 + Q.m11);
    r.m10 = lse2(P.m10 + Q.m00, P.m11 + Q.m10);
    r.m11 = lse2(P.m10 + Q.m01, P.m11 + Q.m11);
    return r;
}

__global__ __launch_bounds__(BLOCK) void crf_fwd(
    const float* __restrict__ emissions,     // [B, S, 2]
    const float* __restrict__ trans_params,  // [4, 2, 2]
    const int*   __restrict__ tags,          // [B, S]
    const int*   __restrict__ who2who,       // [B, S]
    const int*   __restrict__ intime,        // [B, S]
    const int*   __restrict__ distance,      // [B, S]
    float*       __restrict__ out)           // [2, B]
{
    const int b  = blockIdx.x;
    const int t  = threadIdx.x;
    const long base = (long)b * Sn;
    const int s0 = t * CHUNK;

    // bank[sel][i][j] at sbank[sel*4 + i*2 + j]; sel==0 is the zero matrix
    __shared__ __align__(16) float sbank[20];
    __shared__ float wm[4][5];   // per-wave (M00,M01,M10,M11,gold)

    if (t < 20) sbank[t] = (t < 4) ? 0.0f : trans_params[t - 4];
    __syncthreads();

    // ---- coalesced vector loads: each thread owns 8 consecutive steps ----
    const int4* tp = (const int4*)(tags     + base) + t * 2;
    const int4* wp = (const int4*)(who2who  + base) + t * 2;
    const int4* ip = (const int4*)(intime   + base) + t * 2;
    const int4* dp = (const int4*)(distance + base) + t * 2;
    int4 ta = tp[0], tb = tp[1];
    int4 wa = wp[0], wb = wp[1];
    int4 ia = ip[0], ib = ip[1];
    int4 da = dp[0], db = dp[1];

    const float4* ep = (const float4*)(emissions + base * 2) + t * 4;
    float4 e0 = ep[0], e1 = ep[1], e2 = ep[2], e3 = ep[3];

    int tagv[CHUNK] = {ta.x, ta.y, ta.z, ta.w, tb.x, tb.y, tb.z, tb.w};
    int wv[CHUNK]   = {wa.x, wa.y, wa.z, wa.w, wb.x, wb.y, wb.z, wb.w};
    int iv[CHUNK]   = {ia.x, ia.y, ia.z, ia.w, ib.x, ib.y, ib.z, ib.w};
    int dv[CHUNK]   = {da.x, da.y, da.z, da.w, db.x, db.y, db.z, db.w};
    float emv[CHUNK][2] = {
        {e0.x, e0.y}, {e0.z, e0.w}, {e1.x, e1.y}, {e1.z, e1.w},
        {e2.x, e2.y}, {e2.z, e2.w}, {e3.x, e3.y}, {e3.z, e3.w}};

    // tag just before this thread's chunk (for the gold transition at k==0)
    int prev_tag = 0;
    if (t > 0) prev_tag = tags[base + s0 - 1];

    Mat M;
    float gold = 0.0f;

    #pragma unroll
    for (int k = 0; k < CHUNK; ++k) {
        int w = wv[k], it = iv[k], d = dv[k];
        int sel = (w == -1) ? 0 : (w == 1) ? 1 : (it == 0) ? 2 : (d == 0) ? 3 : 4;

        float4 trv = *(const float4*)(sbank + sel * 4);  // t00,t01,t10,t11
        float t00 = trv.x, t01 = trv.y, t10 = trv.z, t11 = trv.w;
        float ek0 = emv[k][0], ek1 = emv[k][1];

        if (k == 0) {
            // chunk matrix starts as the first step matrix (no -inf identity)
            M.m00 = ek0 + t00; M.m01 = ek1 + t01;
            M.m10 = ek0 + t10; M.m11 = ek1 + t11;
        } else {
            float n00 = ek0 + lse2(M.m00 + t00, M.m01 + t10);
            float n01 = ek1 + lse2(M.m00 + t01, M.m01 + t11);
            float n10 = ek0 + lse2(M.m10 + t00, M.m11 + t10);
            float n11 = ek1 + lse2(M.m10 + t01, M.m11 + t11);
            M.m00 = n00; M.m01 = n01; M.m10 = n10; M.m11 = n11;
        }

        // gold path contributions
        int tg = tagv[k];
        gold += tg ? ek1 : ek0;
        if (k > 0 || t > 0) {               // no transition at global s==0
            int pt = (k == 0) ? prev_tag : tagv[k - 1];
            float trg = pt ? (tg ? trv.w : trv.z) : (tg ? trv.y : trv.x);
            gold += trg;
        }
    }

    // ---- order-preserving xor-shuffle reduction across the 64-lane wave ----
    // Invariant: after mask m, each lane holds the in-order composition of its
    // aligned group of 2m chunks. Lower-half group always composes on the left.
    #pragma unroll
    for (int m = 1; m < 64; m <<= 1) {
        Mat O;
        O.m00 = __shfl_xor(M.m00, m);
        O.m01 = __shfl_xor(M.m01, m);
        O.m10 = __shfl_xor(M.m10, m);
        O.m11 = __shfl_xor(M.m11, m);
        float og = __shfl_xor(gold, m);
        bool upper = (t & m) != 0;
        Mat Lo = upper ? O : M;
        Mat Hi = upper ? M : O;
        M = compose(Lo, Hi);
        gold += og;
    }

    // ---- combine the 4 wave results in order ----
    int wave = t >> 6;
    if ((t & 63) == 0) {
        wm[wave][0] = M.m00; wm[wave][1] = M.m01;
        wm[wave][2] = M.m10; wm[wave][3] = M.m11;
        wm[wave][4] = gold;
    }
    __syncthreads();

    if (t == 0) {
        Mat R = {wm[0][0], wm[0][1], wm[0][2], wm[0][3]};
        float g = wm[0][4];
        #pragma unroll
        for (int q = 1; q < 4; ++q) {
            Mat Q = {wm[q][0], wm[q][1], wm[q][2], wm[q][3]};
            R = compose(R, Q);
            g += wm[q][4];
        }
        // total = lse over all 4 entries (alpha0 = zeros)
        float mx = fmaxf(fmaxf(R.m00, R.m01), fmaxf(R.m10, R.m11));
        float tot = mx + __logf(__expf(R.m00 - mx) + __expf(R.m01 - mx) +
                                __expf(R.m10 - mx) + __expf(R.m11 - mx));
        out[b]      = g;    // gold_score
        out[Bn + b] = tot;  // total_score
    }
}

extern "C" void kernel_launch(void* const* d_in, const int* in_sizes, int n_in,
                              void* d_out, int out_size, void* d_ws, size_t ws_size,
                              hipStream_t stream) {
    const float* emissions    = (const float*)d_in[0];
    const float* trans_params = (const float*)d_in[1];
    const int*   tags         = (const int*)d_in[2];
    const int*   who2who      = (const int*)d_in[3];
    const int*   intime       = (const int*)d_in[4];
    const int*   distance     = (const int*)d_in[5];
    float* out = (float*)d_out;

    crf_fwd<<<dim3(Bn), dim3(BLOCK), 0, stream>>>(
        emissions, trans_params, tags, who2who, intime, distance, out);
}

// Round 2
// 202.383 us; speedup vs baseline: 1.0141x; 1.0141x over previous
//
#include <hip/hip_runtime.h>
#include <math.h>

// Problem constants (match reference setup_inputs)
#define Bn 4096
#define Sn 2048
#define BLOCK 256
#define CHUNK (Sn / BLOCK)   // 8 steps per thread

__global__ __launch_bounds__(BLOCK) void crf_fwd(
    const float* __restrict__ emissions,     // [B, S, 2]
    const float* __restrict__ trans_params,  // [4, 2, 2]
    const int*   __restrict__ tags,          // [B, S]
    const int*   __restrict__ who2who,       // [B, S]
    const int*   __restrict__ intime,        // [B, S]
    const int*   __restrict__ distance,      // [B, S]
    float*       __restrict__ out)           // [2, B]
{
    const int b  = blockIdx.x;
    const int t  = threadIdx.x;
    const long base = (long)b * Sn;
    const int s0 = t * CHUNK;

    // sel banks: [sel][i][j] at [sel*4 + i*2 + j]; sel==0 is zero/ones matrix
    __shared__ __align__(16) float lbank[20];  // log-domain (for gold path)
    __shared__ __align__(16) float ebank[20];  // exp(trans) (for forward scan)
    __shared__ float wm[4][6];   // per-wave (m00,m01,m10,m11, L, gold)

    if (t < 20) {
        float v = (t < 4) ? 0.0f : trans_params[t - 4];
        lbank[t] = v;
        ebank[t] = __expf(v);    // sel 0 -> all-ones matrix
    }
    __syncthreads();

    // ---- coalesced vector loads: each thread owns 8 consecutive steps ----
    const int4* tp = (const int4*)(tags     + base) + t * 2;
    const int4* wp = (const int4*)(who2who  + base) + t * 2;
    const int4* ip = (const int4*)(intime   + base) + t * 2;
    const int4* dp = (const int4*)(distance + base) + t * 2;
    int4 ta = tp[0], tb = tp[1];
    int4 wa = wp[0], wb = wp[1];
    int4 ia = ip[0], ib = ip[1];
    int4 da = dp[0], db = dp[1];

    const float4* ep = (const float4*)(emissions + base * 2) + t * 4;
    float4 e0 = ep[0], e1 = ep[1], e2 = ep[2], e3 = ep[3];

    int tagv[CHUNK] = {ta.x, ta.y, ta.z, ta.w, tb.x, tb.y, tb.z, tb.w};
    int wv[CHUNK]   = {wa.x, wa.y, wa.z, wa.w, wb.x, wb.y, wb.z, wb.w};
    int iv[CHUNK]   = {ia.x, ia.y, ia.z, ia.w, ib.x, ib.y, ib.z, ib.w};
    int dv[CHUNK]   = {da.x, da.y, da.z, da.w, db.x, db.y, db.z, db.w};
    float emv[CHUNK][2] = {
        {e0.x, e0.y}, {e0.z, e0.w}, {e1.x, e1.y}, {e1.z, e1.w},
        {e2.x, e2.y}, {e2.z, e2.w}, {e3.x, e3.y}, {e3.z, e3.w}};

    // tag just before this thread's chunk (for the gold transition at k==0)
    int prev_tag = 0;
    if (t > 0) prev_tag = tags[base + s0 - 1];

    // ---- linear-domain chunk scan ----
    // M holds the chunk's transfer matrix in probability space.
    // Worst-case growth per step <= ~850x; over 8 steps < 3e23 -- fp32 safe.
    float m00, m01, m10, m11;
    float gold = 0.0f;

    #pragma unroll
    for (int k = 0; k < CHUNK; ++k) {
        int w = wv[k], it = iv[k], d = dv[k];
        int sel = (w == -1) ? 0 : (w == 1) ? 1 : (it == 0) ? 2 : (d == 0) ? 3 : 4;

        float4 P = *(const float4*)(ebank + sel * 4);  // exp(t00,t01,t10,t11)
        float ek0 = emv[k][0], ek1 = emv[k][1];
        float x0 = __expf(ek0), x1 = __expf(ek1);

        if (k == 0) {
            m00 = P.x * x0; m01 = P.y * x1;
            m10 = P.z * x0; m11 = P.w * x1;
        } else {
            float n00 = fmaf(m00, P.x, m01 * P.z) * x0;
            float n01 = fmaf(m00, P.y, m01 * P.w) * x1;
            float n10 = fmaf(m10, P.x, m11 * P.z) * x0;
            float n11 = fmaf(m10, P.y, m11 * P.w) * x1;
            m00 = n00; m01 = n01; m10 = n10; m11 = n11;
        }

        // gold path contributions (log domain, unchanged from passing round)
        int tg = tagv[k];
        gold += tg ? ek1 : ek0;
        if (k > 0 || t > 0) {               // no transition at global s==0
            int pt = (k == 0) ? prev_tag : tagv[k - 1];
            gold += lbank[(sel << 2) + (pt << 1) + tg];
        }
    }

    // normalize chunk matrix once; carry scale in log space
    float mx  = fmaxf(fmaxf(m00, m01), fmaxf(m10, m11));
    float inv = 1.0f / mx;
    float L   = __logf(mx);
    m00 *= inv; m01 *= inv; m10 *= inv; m11 *= inv;

    // ---- order-preserving xor-shuffle reduction (plain 2x2 matmuls) ----
    // Normalized matrices: max entry <= 1 and entries within ~10x of each
    // other (state mixing), so 6 unnormalized rounds stay in fp32 range.
    #pragma unroll
    for (int m = 1; m < 64; m <<= 1) {
        float o00 = __shfl_xor(m00, m);
        float o01 = __shfl_xor(m01, m);
        float o10 = __shfl_xor(m10, m);
        float o11 = __shfl_xor(m11, m);
        float oL  = __shfl_xor(L, m);
        float og  = __shfl_xor(gold, m);
        bool up = (t & m) != 0;
        float a00 = up ? o00 : m00, a01 = up ? o01 : m01;
        float a10 = up ? o10 : m10, a11 = up ? o11 : m11;
        float b00 = up ? m00 : o00, b01 = up ? m01 : o01;
        float b10 = up ? m10 : o10, b11 = up ? m11 : o11;
        m00 = fmaf(a00, b00, a01 * b10);
        m01 = fmaf(a00, b01, a01 * b11);
        m10 = fmaf(a10, b00, a11 * b10);
        m11 = fmaf(a10, b01, a11 * b11);
        L += oL;
        gold += og;
    }

    // ---- combine the 4 wave results in order ----
    int wave = t >> 6;
    if ((t & 63) == 0) {
        wm[wave][0] = m00; wm[wave][1] = m01;
        wm[wave][2] = m10; wm[wave][3] = m11;
        wm[wave][4] = L;   wm[wave][5] = gold;
    }
    __syncthreads();

    if (t == 0) {
        float r00 = wm[0][0], r01 = wm[0][1], r10 = wm[0][2], r11 = wm[0][3];
        float Ls = wm[0][4], g = wm[0][5];
        #pragma unroll
        for (int q = 1; q < 4; ++q) {
            float q00 = wm[q][0], q01 = wm[q][1], q10 = wm[q][2], q11 = wm[q][3];
            float n00 = fmaf(r00, q00, r01 * q10);
            float n01 = fmaf(r00, q01, r01 * q11);
            float n10 = fmaf(r10, q00, r11 * q10);
            float n11 = fmaf(r10, q01, r11 * q11);
            r00 = n00; r01 = n01; r10 = n10; r11 = n11;
            Ls += wm[q][4];
            g  += wm[q][5];
        }
        // total = L + log(sum of entries)   (alpha0 = zeros)
        float tot = Ls + __logf(r00 + r01 + r10 + r11);
        out[b]      = g;    // gold_score
        out[Bn + b] = tot;  // total_score
    }
}

extern "C" void kernel_launch(void* const* d_in, const int* in_sizes, int n_in,
                              void* d_out, int out_size, void* d_ws, size_t ws_size,
                              hipStream_t stream) {
    const float* emissions    = (const float*)d_in[0];
    const float* trans_params = (const float*)d_in[1];
    const int*   tags         = (const int*)d_in[2];
    const int*   who2who      = (const int*)d_in[3];
    const int*   intime       = (const int*)d_in[4];
    const int*   distance     = (const int*)d_in[5];
    float* out = (float*)d_out;

    crf_fwd<<<dim3(Bn), dim3(BLOCK), 0, stream>>>(
        emissions, trans_params, tags, who2who, intime, distance, out);
}

// Round 3
// 200.797 us; speedup vs baseline: 1.0221x; 1.0079x over previous
//
#include <hip/hip_runtime.h>
#include <math.h>

// Problem constants (match reference setup_inputs)
#define Bn 4096
#define Sn 2048
#define BLOCK 256
#define CHUNK (Sn / BLOCK)   // 8 steps per thread

// __launch_bounds__(256, 2): min 2 waves/EU -> VGPR budget up to 256.
// Round 2 post-mortem: default heuristic allocated 36 VGPRs (< the 48 needed
// just to hold this thread's 13 vector loads), forcing serialized load
// batches -> latency-bound at 17% HBM. This bound un-handcuffs the scheduler.
__global__ __launch_bounds__(BLOCK, 2) void crf_fwd(
    const float* __restrict__ emissions,     // [B, S, 2]
    const float* __restrict__ trans_params,  // [4, 2, 2]
    const int*   __restrict__ tags,          // [B, S]
    const int*   __restrict__ who2who,       // [B, S]
    const int*   __restrict__ intime,        // [B, S]
    const int*   __restrict__ distance,      // [B, S]
    float*       __restrict__ out)           // [2, B]
{
    const int b  = blockIdx.x;
    const int t  = threadIdx.x;
    const long base = (long)b * Sn;
    const int s0 = t * CHUNK;

    // sel banks: [sel][i][j] at [sel*4 + i*2 + j]; sel==0 is zero/ones matrix
    __shared__ __align__(16) float lbank[20];  // log-domain (for gold path)
    __shared__ __align__(16) float ebank[20];  // exp(trans) (for forward scan)
    __shared__ float wm[4][6];   // per-wave (m00,m01,m10,m11, L, gold)

    // ---- phase 1: issue ALL global loads up front (independent) ----
    const int4* tp = (const int4*)(tags     + base) + t * 2;
    const int4* wp = (const int4*)(who2who  + base) + t * 2;
    const int4* ip = (const int4*)(intime   + base) + t * 2;
    const int4* dp = (const int4*)(distance + base) + t * 2;
    const float4* ep = (const float4*)(emissions + base * 2) + t * 4;

    float4 e0 = ep[0], e1 = ep[1], e2 = ep[2], e3 = ep[3];
    int4 ta = tp[0], tb = tp[1];
    int4 wa = wp[0], wb = wp[1];
    int4 ia = ip[0], ib = ip[1];
    int4 da = dp[0], db = dp[1];
    // tag just before this thread's chunk (same cache lines as ta/tb of t-1)
    int prev_tag = (t > 0) ? tags[base + s0 - 1] : 0;

    // ---- bank init (overlaps with the loads above) ----
    if (t < 20) {
        float v = (t < 4) ? 0.0f : trans_params[t - 4];
        lbank[t] = v;
        ebank[t] = __expf(v);    // sel 0 -> all-ones matrix
    }
    __syncthreads();

    int wv[CHUNK]   = {wa.x, wa.y, wa.z, wa.w, wb.x, wb.y, wb.z, wb.w};
    int iv[CHUNK]   = {ia.x, ia.y, ia.z, ia.w, ib.x, ib.y, ib.z, ib.w};
    int dv[CHUNK]   = {da.x, da.y, da.z, da.w, db.x, db.y, db.z, db.w};
    int tagv[CHUNK] = {ta.x, ta.y, ta.z, ta.w, tb.x, tb.y, tb.z, tb.w};
    float emv[CHUNK][2] = {
        {e0.x, e0.y}, {e0.z, e0.w}, {e1.x, e1.y}, {e1.z, e1.w},
        {e2.x, e2.y}, {e2.z, e2.w}, {e3.x, e3.y}, {e3.z, e3.w}};

    // ---- phase 2: all sels, then all LDS reads (independent b128s) ----
    int sel[CHUNK];
    #pragma unroll
    for (int k = 0; k < CHUNK; ++k) {
        int w = wv[k], it = iv[k], d = dv[k];
        sel[k] = (w == -1) ? 0 : (w == 1) ? 1 : (it == 0) ? 2 : (d == 0) ? 3 : 4;
    }
    float4 P[CHUNK];
    #pragma unroll
    for (int k = 0; k < CHUNK; ++k)
        P[k] = *(const float4*)(ebank + sel[k] * 4);

    // ---- phase 3: all emission exps (independent transcendentals) ----
    float x[CHUNK][2];
    #pragma unroll
    for (int k = 0; k < CHUNK; ++k) {
        x[k][0] = __expf(emv[k][0]);
        x[k][1] = __expf(emv[k][1]);
    }

    // ---- phase 4: short dependent chain -- linear-domain chunk scan ----
    // Worst-case growth per step <= ~1500x; over 8 steps < 3e25 -- fp32 safe.
    float m00 = P[0].x * x[0][0], m01 = P[0].y * x[0][1];
    float m10 = P[0].z * x[0][0], m11 = P[0].w * x[0][1];
    float gold = 0.0f;

    #pragma unroll
    for (int k = 1; k < CHUNK; ++k) {
        float n00 = fmaf(m00, P[k].x, m01 * P[k].z) * x[k][0];
        float n01 = fmaf(m00, P[k].y, m01 * P[k].w) * x[k][1];
        float n10 = fmaf(m10, P[k].x, m11 * P[k].z) * x[k][0];
        float n11 = fmaf(m10, P[k].y, m11 * P[k].w) * x[k][1];
        m00 = n00; m01 = n01; m10 = n10; m11 = n11;
    }

    // gold path (log domain)
    #pragma unroll
    for (int k = 0; k < CHUNK; ++k) {
        int tg = tagv[k];
        gold += tg ? emv[k][1] : emv[k][0];
        if (k > 0 || t > 0) {               // no transition at global s==0
            int pt = (k == 0) ? prev_tag : tagv[k - 1];
            gold += lbank[(sel[k] << 2) + (pt << 1) + tg];
        }
    }

    // normalize chunk matrix once; carry scale in log space
    float mx  = fmaxf(fmaxf(m00, m01), fmaxf(m10, m11));
    float inv = 1.0f / mx;
    float L   = __logf(mx);
    m00 *= inv; m01 *= inv; m10 *= inv; m11 *= inv;

    // ---- order-preserving xor-shuffle reduction (plain 2x2 matmuls) ----
    #pragma unroll
    for (int m = 1; m < 64; m <<= 1) {
        float o00 = __shfl_xor(m00, m);
        float o01 = __shfl_xor(m01, m);
        float o10 = __shfl_xor(m10, m);
        float o11 = __shfl_xor(m11, m);
        float oL  = __shfl_xor(L, m);
        float og  = __shfl_xor(gold, m);
        bool up = (t & m) != 0;
        float a00 = up ? o00 : m00, a01 = up ? o01 : m01;
        float a10 = up ? o10 : m10, a11 = up ? o11 : m11;
        float b00 = up ? m00 : o00, b01 = up ? m01 : o01;
        float b10 = up ? m10 : o10, b11 = up ? m11 : o11;
        m00 = fmaf(a00, b00, a01 * b10);
        m01 = fmaf(a00, b01, a01 * b11);
        m10 = fmaf(a10, b00, a11 * b10);
        m11 = fmaf(a10, b01, a11 * b11);
        L += oL;
        gold += og;
    }

    // ---- combine the 4 wave results in order ----
    int wave = t >> 6;
    if ((t & 63) == 0) {
        wm[wave][0] = m00; wm[wave][1] = m01;
        wm[wave][2] = m10; wm[wave][3] = m11;
        wm[wave][4] = L;   wm[wave][5] = gold;
    }
    __syncthreads();

    if (t == 0) {
        float r00 = wm[0][0], r01 = wm[0][1], r10 = wm[0][2], r11 = wm[0][3];
        float Ls = wm[0][4], g = wm[0][5];
        #pragma unroll
        for (int q = 1; q < 4; ++q) {
            float q00 = wm[q][0], q01 = wm[q][1], q10 = wm[q][2], q11 = wm[q][3];
            float n00 = fmaf(r00, q00, r01 * q10);
            float n01 = fmaf(r00, q01, r01 * q11);
            float n10 = fmaf(r10, q00, r11 * q10);
            float n11 = fmaf(r10, q01, r11 * q11);
            r00 = n00; r01 = n01; r10 = n10; r11 = n11;
            Ls += wm[q][4];
            g  += wm[q][5];
        }
        // total = L + log(sum of entries)   (alpha0 = zeros)
        float tot = Ls + __logf(r00 + r01 + r10 + r11);
        out[b]      = g;    // gold_score
        out[Bn + b] = tot;  // total_score
    }
}

extern "C" void kernel_launch(void* const* d_in, const int* in_sizes, int n_in,
                              void* d_out, int out_size, void* d_ws, size_t ws_size,
                              hipStream_t stream) {
    const float* emissions    = (const float*)d_in[0];
    const float* trans_params = (const float*)d_in[1];
    const int*   tags         = (const int*)d_in[2];
    const int*   who2who      = (const int*)d_in[3];
    const int*   intime       = (const int*)d_in[4];
    const int*   distance     = (const int*)d_in[5];
    float* out = (float*)d_out;

    crf_fwd<<<dim3(Bn), dim3(BLOCK), 0, stream>>>(
        emissions, trans_params, tags, who2who, intime, distance, out);
}